// Round 8
// baseline (205.225 us; speedup 1.0000x reference)
//
#include <hip/hip_runtime.h>
#include <cstdint>

#define DEV static __device__ __forceinline__
#define WAITVM(N) asm volatile("s_waitcnt vmcnt(" #N ")" ::: "memory")

typedef float f32x4 __attribute__((ext_vector_type(4)));
typedef short bf16x8 __attribute__((ext_vector_type(8)));   // 8 bf16 in 4 VGPRs

constexpr int Bsz = 16384;
constexpr int Dd  = 1024;   // D
constexpr int DKd = 1024;   // DK

// float -> bf16 bits, round-to-nearest-even
DEV unsigned short f2bf(float f) {
    uint32_t u = __builtin_bit_cast(uint32_t, f);
    u += 0x7FFFu + ((u >> 16) & 1u);
    return (unsigned short)(u >> 16);
}

// async global->LDS, 16 bytes per lane (dest must be linear: base + lane*16)
DEV void async_lds16(const void* g, void* l) {
    __builtin_amdgcn_global_load_lds(
        (const __attribute__((address_space(1))) void*)g,
        (__attribute__((address_space(3))) void*)l,
        16, 0, 0);
}

// ---------------- prep (single kernel): mixed = bf16(mix*x + (1-mix)*x_prev),
// WkB = bf16(Wk), WfB = bf16(Wf) ----------------
__global__ void k_prep(const float4* __restrict__ x, const float4* __restrict__ xp,
                       const float* __restrict__ mixp,
                       const float4* __restrict__ Wk, const float4* __restrict__ Wf,
                       unsigned short* __restrict__ mixed,
                       unsigned short* __restrict__ WkB,
                       unsigned short* __restrict__ WfB) {
    constexpr int n_mix = Bsz * Dd / 4;       // 4194304
    constexpr int n_w   = DKd * Dd / 4;       // 262144
    constexpr int total = n_mix + 2 * n_w;
    const float m = *mixp, m1 = 1.0f - m;
    int i = blockIdx.x * blockDim.x + threadIdx.x;
    const int st = gridDim.x * blockDim.x;
    for (; i < total; i += st) {
        float4 a;
        unsigned short* dst;
        int idx;
        if (i < n_mix) {
            float4 xa = x[i], xb = xp[i];
            a.x = m * xa.x + m1 * xb.x;
            a.y = m * xa.y + m1 * xb.y;
            a.z = m * xa.z + m1 * xb.z;
            a.w = m * xa.w + m1 * xb.w;
            dst = mixed; idx = i;
        } else if (i < n_mix + n_w) {
            a = Wk[i - n_mix]; dst = WkB; idx = i - n_mix;
        } else {
            a = Wf[i - n_mix - n_w]; dst = WfB; idx = i - n_mix - n_w;
        }
        ushort4 o;
        o.x = f2bf(a.x); o.y = f2bf(a.y); o.z = f2bf(a.z); o.w = f2bf(a.w);
        reinterpret_cast<ushort4*>(dst)[idx] = o;
    }
}

// ---- NT GEMM, deep-prefetch ring pipeline at 256x256 ----
// C[M,N] = A[M,1024] * Bw[N,1024]^T. 32 K-tiles of BK=32; 8 waves (2x4),
// per-wave output 128x64. LDS: ring of 4 slots per operand (4 x 16 KB x 2 =
// 128 KB), 1 block/CU. Per tile t: stage(t+3) issued FIRST (slot (t+3)&3,
// freed at end of t-1), then 12 ds_read_b128 + 32 MFMA (setprio), then
// vmcnt(8) (t+1 resident; t+2,t+3 stay in flight) + ONE barrier. Loads are
// waited 4-6 phases after issue (~1000+ cyc) -> HBM latency covered (T3+T4).
// Bank swizzle (r7, measured 0 conflicts): physgrp = g ^ (r&3) ^ ((r>>2)&3),
// involution pre-applied on the global source, LDS linear (rule #21).
// EPI==1: RWKV epilogue; EPI==0: bias epilogue.
template <int EPI>
__global__ __launch_bounds__(512)
void k_gemm(const unsigned short* __restrict__ A,   // [M,1024] bf16
            const unsigned short* __restrict__ Bw,  // [N,1024] bf16
            const float* __restrict__ bias,
            const float* __restrict__ num, const float* __restrict__ den,
            const float* __restrict__ bonus, const float* __restrict__ decayp,
            float* __restrict__ o0, float* __restrict__ o1,
            unsigned short* __restrict__ orw)
{
    __shared__ __align__(16) unsigned short As[4][256 * 32];  // 64 KB
    __shared__ __align__(16) unsigned short Bs[4][256 * 32];  // 64 KB

    const int tid = threadIdx.x;
    // bijective XCD swizzle: grid 256 (64 rb x 4 cb); each XCD gets a
    // contiguous 32-wg chunk -> B fully L2-resident per XCD.
    const int bid = (int)blockIdx.x;
    const int wg  = (bid & 7) * 32 + (bid >> 3);
    const int cb  = wg & 3;
    const int rb  = wg >> 2;
    const int row0 = rb * 256;
    const int col0 = cb * 256;

    const int lane = tid & 63;
    const int wid  = tid >> 6;                      // 0..7
    const int wr = wid >> 2, wc = wid & 3;          // 2x4 wave grid: 128x64 per wave
    const int l16 = lane & 15, lq = lane >> 4;

    // ---- staging addressing (hoisted). Per tile per operand: 1024 16B-segs;
    // thread handles segs tid (rows 0..127) and tid+512 (rows 128..255).
    // seg -> row r = seg>>2, physgrp = seg&3; source grp = physgrp ^ (r&3) ^ ((r>>2)&3).
    const int r0   = tid >> 2;                      // 0..127
    const int glog = (tid & 3) ^ (r0 & 3) ^ ((r0 >> 2) & 3);
    const unsigned short* pa0 = A  + (size_t)(row0 + r0) * 1024 + glog * 8;
    const unsigned short* pa1 = A  + (size_t)(row0 + r0 + 128) * 1024 + glog * 8;
    const unsigned short* pb0 = Bw + (size_t)(col0 + r0) * 1024 + glog * 8;
    const unsigned short* pb1 = Bw + (size_t)(col0 + r0 + 128) * 1024 + glog * 8;

    // ---- ds_read offsets: row = wbase + m*16 + l16; physgrp = lq ^ (l16&3) ^ ((l16>>2)&3)
    const int pg    = lq ^ (l16 & 3) ^ ((l16 >> 2) & 3);
    const int abase = (wr * 128 + l16) * 32 + pg * 8;   // + m*512 (shorts)
    const int bbase = (wc * 64 + l16) * 32 + pg * 8;    // + n*512

    f32x4 acc[8][4] = {};

    auto stage = [&](int t) {
        const int slot = t & 3;
        const int off  = t * 32;                    // shorts along K
        async_lds16(pa0 + off, &As[slot][tid * 8]);
        async_lds16(pa1 + off, &As[slot][(tid + 512) * 8]);
        async_lds16(pb0 + off, &Bs[slot][tid * 8]);
        async_lds16(pb1 + off, &Bs[slot][(tid + 512) * 8]);
    };

    // prologue: tiles 0,1,2 in flight (12 loads/thread)
    stage(0); stage(1); stage(2);
    WAITVM(8);                                      // tile 0 resident
    __builtin_amdgcn_s_barrier();
    __builtin_amdgcn_sched_barrier(0);

#pragma unroll 1
    for (int t = 0; t < 32; ++t) {
        if (t < 29) stage(t + 3);                   // issue-early, deep prefetch
        const unsigned short* Ab = &As[t & 3][abase];
        const unsigned short* Bb = &Bs[t & 3][bbase];
        bf16x8 af[8], bfr[4];
#pragma unroll
        for (int n = 0; n < 4; ++n)
            bfr[n] = *reinterpret_cast<const bf16x8*>(Bb + n * 512);
#pragma unroll
        for (int m = 0; m < 8; ++m)
            af[m] = *reinterpret_cast<const bf16x8*>(Ab + m * 512);
        __builtin_amdgcn_s_setprio(1);
#pragma unroll
        for (int m = 0; m < 8; ++m)
#pragma unroll
            for (int n = 0; n < 4; ++n)
                acc[m][n] = __builtin_amdgcn_mfma_f32_16x16x32_bf16(
                    af[m], bfr[n], acc[m][n], 0, 0, 0);
        __builtin_amdgcn_s_setprio(0);
        if (t < 29)      { WAITVM(8); }             // tile t+1 resident
        else if (t == 29){ WAITVM(4); }
        else if (t == 30){ WAITVM(0); }
        if (t < 31) {
            __builtin_amdgcn_s_barrier();
            __builtin_amdgcn_sched_barrier(0);
        }
    }

    // ---------------- epilogue ----------------
    // C/D layout: col = lane&15, row = (lane>>4)*4 + reg  (guide §3, m89-verified)
    const int baserow = row0 + wr * 128 + lq * 4;
    const int basecol = col0 + wc * 64 + l16;

    if constexpr (EPI == 1) {
        const float w_decay = __expf(-__expf(*decayp));
        float cbias[4], cebon[4];
#pragma unroll
        for (int n = 0; n < 4; ++n) {
            cbias[n] = bias[basecol + n * 16];
            cebon[n] = __expf(bonus[basecol + n * 16]);
        }
#pragma unroll
        for (int m = 0; m < 8; ++m) {
#pragma unroll
            for (int r = 0; r < 4; ++r) {
                const size_t rowoff = (size_t)(baserow + m * 16 + r) * 1024;
#pragma unroll
                for (int n = 0; n < 4; ++n) {
                    const size_t idx = rowoff + basecol + n * 16;
                    const float Kv  = acc[m][n][r] + cbias[n];
                    const float eK  = __expf(Kv);
                    const float ebk = cebon[n] * eK;       // exp(bonus + K)
                    const float nb  = num[idx];
                    const float db  = den[idx];
                    const float wkv = (nb + ebk * Kv) * __builtin_amdgcn_rcpf(db + ebk);
                    const float sig = eK * __builtin_amdgcn_rcpf(1.0f + eK);
                    o0[idx]  = w_decay * nb + eK * Kv;     // num_new
                    o1[idx]  = w_decay * db + eK;          // den_new
                    orw[idx] = f2bf(sig * wkv);            // rwkv (bf16 for GEMM2)
                }
            }
        }
    } else {
        float cbias[4];
#pragma unroll
        for (int n = 0; n < 4; ++n) cbias[n] = bias[basecol + n * 16];
#pragma unroll
        for (int m = 0; m < 8; ++m) {
#pragma unroll
            for (int r = 0; r < 4; ++r) {
                const size_t rowoff = (size_t)(baserow + m * 16 + r) * 1024;
#pragma unroll
                for (int n = 0; n < 4; ++n)
                    o0[rowoff + basecol + n * 16] = acc[m][n][r] + cbias[n];
            }
        }
    }
}

extern "C" void kernel_launch(void* const* d_in, const int* in_sizes, int n_in,
                              void* d_out, int out_size, void* d_ws, size_t ws_size,
                              hipStream_t stream) {
    const float* x     = (const float*)d_in[0];
    const float* xprev = (const float*)d_in[1];
    const float* num   = (const float*)d_in[2];
    const float* den   = (const float*)d_in[3];
    const float* Wk    = (const float*)d_in[4];
    const float* bk    = (const float*)d_in[5];
    const float* mixk  = (const float*)d_in[6];
    const float* Wf    = (const float*)d_in[7];
    const float* bf_   = (const float*)d_in[8];
    const float* bonus = (const float*)d_in[9];
    const float* decay = (const float*)d_in[10];

    float* out    = (float*)d_out;                      // [B, D]
    float* numnew = out + (size_t)Bsz * Dd;             // [B, DK]
    float* dennew = numnew + (size_t)Bsz * DKd;         // [B, DK]

    char* ws = (char*)d_ws;
    unsigned short* mixed = (unsigned short*)ws;                       // 32 MB
    unsigned short* WkB   = (unsigned short*)(ws + (size_t)Bsz * Dd * 2);
    unsigned short* WfB   = WkB + (size_t)DKd * Dd;                    // +2 MB
    unsigned short* rwkv  = WfB + (size_t)Dd * DKd;                    // +2 MB

    k_prep<<<2048, 256, 0, stream>>>((const float4*)x, (const float4*)xprev, mixk,
                                     (const float4*)Wk, (const float4*)Wf,
                                     mixed, WkB, WfB);

    const int grid = (Bsz / 256) * (DKd / 256);   // 256 blocks, 1 per CU
    k_gemm<1><<<grid, 512, 0, stream>>>(mixed, WkB, bk, num, den, bonus, decay,
                                        numnew, dennew, rwkv);
    k_gemm<0><<<grid, 512, 0, stream>>>(rwkv, WfB, bf_, nullptr, nullptr, nullptr,
                                        nullptr, out, nullptr, nullptr);
}

// Round 9
// 192.358 us; speedup vs baseline: 1.0669x; 1.0669x over previous
//
#include <hip/hip_runtime.h>
#include <cstdint>

#define DEV static __device__ __forceinline__
#define WAITVM(N) asm volatile("s_waitcnt vmcnt(" #N ")" ::: "memory")

typedef float f32x4 __attribute__((ext_vector_type(4)));
typedef short bf16x8 __attribute__((ext_vector_type(8)));   // 8 bf16 in 4 VGPRs

constexpr int Bsz = 16384;
constexpr int Dd  = 1024;   // D
constexpr int DKd = 1024;   // DK

// float -> bf16 bits, round-to-nearest-even
DEV unsigned short f2bf(float f) {
    uint32_t u = __builtin_bit_cast(uint32_t, f);
    u += 0x7FFFu + ((u >> 16) & 1u);
    return (unsigned short)(u >> 16);
}

// async global->LDS, 16 bytes per lane (dest must be linear: base + lane*16)
DEV void async_lds16(const void* g, void* l) {
    __builtin_amdgcn_global_load_lds(
        (const __attribute__((address_space(1))) void*)g,
        (__attribute__((address_space(3))) void*)l,
        16, 0, 0);
}

// ---------------- prep (single kernel): mixed = bf16(mix*x + (1-mix)*x_prev),
// WkB = bf16(Wk), WfB = bf16(Wf) ----------------
__global__ void k_prep(const float4* __restrict__ x, const float4* __restrict__ xp,
                       const float* __restrict__ mixp,
                       const float4* __restrict__ Wk, const float4* __restrict__ Wf,
                       unsigned short* __restrict__ mixed,
                       unsigned short* __restrict__ WkB,
                       unsigned short* __restrict__ WfB) {
    constexpr int n_mix = Bsz * Dd / 4;       // 4194304
    constexpr int n_w   = DKd * Dd / 4;       // 262144
    constexpr int total = n_mix + 2 * n_w;
    const float m = *mixp, m1 = 1.0f - m;
    int i = blockIdx.x * blockDim.x + threadIdx.x;
    const int st = gridDim.x * blockDim.x;
    for (; i < total; i += st) {
        float4 a;
        unsigned short* dst;
        int idx;
        if (i < n_mix) {
            float4 xa = x[i], xb = xp[i];
            a.x = m * xa.x + m1 * xb.x;
            a.y = m * xa.y + m1 * xb.y;
            a.z = m * xa.z + m1 * xb.z;
            a.w = m * xa.w + m1 * xb.w;
            dst = mixed; idx = i;
        } else if (i < n_mix + n_w) {
            a = Wk[i - n_mix]; dst = WkB; idx = i - n_mix;
        } else {
            a = Wf[i - n_mix - n_w]; dst = WfB; idx = i - n_mix - n_w;
        }
        ushort4 o;
        o.x = f2bf(a.x); o.y = f2bf(a.y); o.z = f2bf(a.z); o.w = f2bf(a.w);
        reinterpret_cast<ushort4*>(dst)[idx] = o;
    }
}

// ==================== GEMM1: r8 deep-prefetch ring (verbatim), RWKV epilogue ====
// 32 K-tiles of BK=32; ring of 4 LDS slots/operand; stage(t+3) issue-early;
// vmcnt(8) counted; one barrier/tile. Measured ~60 us (r8 profile, by subtraction).
__global__ __launch_bounds__(512)
void k_gemm1(const unsigned short* __restrict__ A,   // mixed [M,1024] bf16
             const unsigned short* __restrict__ Bw,  // WkB [N,1024] bf16
             const float* __restrict__ bias,
             const float* __restrict__ num, const float* __restrict__ den,
             const float* __restrict__ bonus, const float* __restrict__ decayp,
             float* __restrict__ o0, float* __restrict__ o1,
             unsigned short* __restrict__ orw)
{
    __shared__ __align__(16) unsigned short As[4][256 * 32];  // 64 KB
    __shared__ __align__(16) unsigned short Bs[4][256 * 32];  // 64 KB

    const int tid = threadIdx.x;
    const int bid = (int)blockIdx.x;
    const int wg  = (bid & 7) * 32 + (bid >> 3);
    const int cb  = wg & 3;
    const int rb  = wg >> 2;
    const int row0 = rb * 256;
    const int col0 = cb * 256;

    const int lane = tid & 63;
    const int wid  = tid >> 6;
    const int wr = wid >> 2, wc = wid & 3;          // 2x4 wave grid: 128x64 per wave
    const int l16 = lane & 15, lq = lane >> 4;

    const int r0   = tid >> 2;                      // 0..127
    const int glog = (tid & 3) ^ (r0 & 3) ^ ((r0 >> 2) & 3);
    const unsigned short* pa0 = A  + (size_t)(row0 + r0) * 1024 + glog * 8;
    const unsigned short* pa1 = A  + (size_t)(row0 + r0 + 128) * 1024 + glog * 8;
    const unsigned short* pb0 = Bw + (size_t)(col0 + r0) * 1024 + glog * 8;
    const unsigned short* pb1 = Bw + (size_t)(col0 + r0 + 128) * 1024 + glog * 8;

    const int pg    = lq ^ (l16 & 3) ^ ((l16 >> 2) & 3);
    const int abase = (wr * 128 + l16) * 32 + pg * 8;   // + m*512 (shorts)
    const int bbase = (wc * 64 + l16) * 32 + pg * 8;    // + n*512

    f32x4 acc[8][4] = {};

    auto stage = [&](int t) {
        const int slot = t & 3;
        const int off  = t * 32;
        async_lds16(pa0 + off, &As[slot][tid * 8]);
        async_lds16(pa1 + off, &As[slot][(tid + 512) * 8]);
        async_lds16(pb0 + off, &Bs[slot][tid * 8]);
        async_lds16(pb1 + off, &Bs[slot][(tid + 512) * 8]);
    };

    stage(0); stage(1); stage(2);
    WAITVM(8);                                      // tile 0 resident
    __builtin_amdgcn_s_barrier();
    __builtin_amdgcn_sched_barrier(0);

#pragma unroll 1
    for (int t = 0; t < 32; ++t) {
        if (t < 29) stage(t + 3);
        const unsigned short* Ab = &As[t & 3][abase];
        const unsigned short* Bb = &Bs[t & 3][bbase];
        bf16x8 af[8], bfr[4];
#pragma unroll
        for (int n = 0; n < 4; ++n)
            bfr[n] = *reinterpret_cast<const bf16x8*>(Bb + n * 512);
#pragma unroll
        for (int m = 0; m < 8; ++m)
            af[m] = *reinterpret_cast<const bf16x8*>(Ab + m * 512);
        __builtin_amdgcn_s_setprio(1);
#pragma unroll
        for (int m = 0; m < 8; ++m)
#pragma unroll
            for (int n = 0; n < 4; ++n)
                acc[m][n] = __builtin_amdgcn_mfma_f32_16x16x32_bf16(
                    af[m], bfr[n], acc[m][n], 0, 0, 0);
        __builtin_amdgcn_s_setprio(0);
        if (t < 29)      { WAITVM(8); }
        else if (t == 29){ WAITVM(4); }
        else if (t == 30){ WAITVM(0); }
        if (t < 31) {
            __builtin_amdgcn_s_barrier();
            __builtin_amdgcn_sched_barrier(0);
        }
    }

    // RWKV epilogue. C/D layout: col = lane&15, row = (lane>>4)*4 + reg
    const int baserow = row0 + wr * 128 + lq * 4;
    const int basecol = col0 + wc * 64 + l16;

    const float w_decay = __expf(-__expf(*decayp));
    float cbias[4], cebon[4];
#pragma unroll
    for (int n = 0; n < 4; ++n) {
        cbias[n] = bias[basecol + n * 16];
        cebon[n] = __expf(bonus[basecol + n * 16]);
    }
#pragma unroll
    for (int m = 0; m < 8; ++m) {
#pragma unroll
        for (int r = 0; r < 4; ++r) {
            const size_t rowoff = (size_t)(baserow + m * 16 + r) * 1024;
#pragma unroll
            for (int n = 0; n < 4; ++n) {
                const size_t idx = rowoff + basecol + n * 16;
                const float Kv  = acc[m][n][r] + cbias[n];
                const float eK  = __expf(Kv);
                const float ebk = cebon[n] * eK;
                const float nb  = num[idx];
                const float db  = den[idx];
                const float wkv = (nb + ebk * Kv) * __builtin_amdgcn_rcpf(db + ebk);
                const float sig = eK * __builtin_amdgcn_rcpf(1.0f + eK);
                o0[idx]  = w_decay * nb + eK * Kv;
                o1[idx]  = w_decay * db + eK;
                orw[idx] = f2bf(sig * wkv);
            }
        }
    }
}

// ==================== GEMM2: r7 2-chunk counted-vmcnt pipeline (verbatim), bias ====
// BK=64 as 2 kk-chunks of 32; LDS [2buf][2kk]; vmcnt(8) counted, 2 barriers/t.
__global__ __launch_bounds__(512, 2)
void k_gemm2(const unsigned short* __restrict__ A,   // rwkv [M,1024] bf16
             const unsigned short* __restrict__ Bw,  // WfB [N,1024] bf16
             const float* __restrict__ bias,
             float* __restrict__ o0)
{
    __shared__ __align__(16) unsigned short As[2][2][256 * 32];  // 64 KB
    __shared__ __align__(16) unsigned short Bs[2][2][256 * 32];  // 64 KB

    const int tid = threadIdx.x;
    const int bid = (int)blockIdx.x;
    const int wg  = (bid & 7) * 32 + (bid >> 3);
    const int cb  = wg & 3;
    const int rb  = wg >> 2;
    const int row0 = rb * 256;
    const int col0 = cb * 256;

    const int lane = tid & 63;
    const int wid  = tid >> 6;
    const int wr = wid >> 2, wc = wid & 3;
    const int l16 = lane & 15, lq = lane >> 4;

    const int r0   = tid >> 2;
    const int glog = (tid & 3) ^ (r0 & 3) ^ ((r0 >> 2) & 3);
    const unsigned short* pa0 = A  + (size_t)(row0 + r0) * 1024 + glog * 8;
    const unsigned short* pa1 = A  + (size_t)(row0 + r0 + 128) * 1024 + glog * 8;
    const unsigned short* pb0 = Bw + (size_t)(col0 + r0) * 1024 + glog * 8;
    const unsigned short* pb1 = Bw + (size_t)(col0 + r0 + 128) * 1024 + glog * 8;

    const int pg    = lq ^ (l16 & 3) ^ ((l16 >> 2) & 3);
    const int abase = (wr * 128 + l16) * 32 + pg * 8;
    const int bbase = (wc * 64 + l16) * 32 + pg * 8;

    f32x4 acc[8][4] = {};

    auto stage = [&](int buf, int kk, int t) {
        const int off = t * 64 + kk * 32;
        async_lds16(pa0 + off, &As[buf][kk][tid * 8]);
        async_lds16(pa1 + off, &As[buf][kk][(tid + 512) * 8]);
        async_lds16(pb0 + off, &Bs[buf][kk][tid * 8]);
        async_lds16(pb1 + off, &Bs[buf][kk][(tid + 512) * 8]);
    };

    auto compute = [&](int buf, int kk) {
        const unsigned short* Ar = &As[buf][kk][abase];
        const unsigned short* Br = &Bs[buf][kk][bbase];
        bf16x8 af[8], bfr[4];
#pragma unroll
        for (int n = 0; n < 4; ++n)
            bfr[n] = *reinterpret_cast<const bf16x8*>(Br + n * 512);
#pragma unroll
        for (int m = 0; m < 8; ++m)
            af[m] = *reinterpret_cast<const bf16x8*>(Ar + m * 512);
        __builtin_amdgcn_s_setprio(1);
#pragma unroll
        for (int m = 0; m < 8; ++m)
#pragma unroll
            for (int n = 0; n < 4; ++n)
                acc[m][n] = __builtin_amdgcn_mfma_f32_16x16x32_bf16(
                    af[m], bfr[n], acc[m][n], 0, 0, 0);
        __builtin_amdgcn_s_setprio(0);
    };

    stage(0, 0, 0); stage(0, 1, 0); stage(1, 0, 1); stage(1, 1, 1);
    WAITVM(12);
    __builtin_amdgcn_s_barrier();
    __builtin_amdgcn_sched_barrier(0);

#pragma unroll 1
    for (int t = 0; t < 14; ++t) {
        const int buf = t & 1;
        compute(buf, 0);
        WAITVM(8);
        __builtin_amdgcn_s_barrier();
        __builtin_amdgcn_sched_barrier(0);
        stage(buf, 0, t + 2);
        compute(buf, 1);
        WAITVM(8);
        __builtin_amdgcn_s_barrier();
        __builtin_amdgcn_sched_barrier(0);
        stage(buf, 1, t + 2);
    }
    compute(0, 0);
    WAITVM(8);  __builtin_amdgcn_s_barrier(); __builtin_amdgcn_sched_barrier(0);
    compute(0, 1);
    WAITVM(4);  __builtin_amdgcn_s_barrier(); __builtin_amdgcn_sched_barrier(0);
    compute(1, 0);
    WAITVM(0);  __builtin_amdgcn_s_barrier(); __builtin_amdgcn_sched_barrier(0);
    compute(1, 1);

    const int baserow = row0 + wr * 128 + lq * 4;
    const int basecol = col0 + wc * 64 + l16;

    float cbias[4];
#pragma unroll
    for (int n = 0; n < 4; ++n) cbias[n] = bias[basecol + n * 16];
#pragma unroll
    for (int m = 0; m < 8; ++m) {
#pragma unroll
        for (int r = 0; r < 4; ++r) {
            const size_t rowoff = (size_t)(baserow + m * 16 + r) * 1024;
#pragma unroll
            for (int n = 0; n < 4; ++n)
                o0[rowoff + basecol + n * 16] = acc[m][n][r] + cbias[n];
        }
    }
}

extern "C" void kernel_launch(void* const* d_in, const int* in_sizes, int n_in,
                              void* d_out, int out_size, void* d_ws, size_t ws_size,
                              hipStream_t stream) {
    const float* x     = (const float*)d_in[0];
    const float* xprev = (const float*)d_in[1];
    const float* num   = (const float*)d_in[2];
    const float* den   = (const float*)d_in[3];
    const float* Wk    = (const float*)d_in[4];
    const float* bk    = (const float*)d_in[5];
    const float* mixk  = (const float*)d_in[6];
    const float* Wf    = (const float*)d_in[7];
    const float* bf_   = (const float*)d_in[8];
    const float* bonus = (const float*)d_in[9];
    const float* decay = (const float*)d_in[10];

    float* out    = (float*)d_out;                      // [B, D]
    float* numnew = out + (size_t)Bsz * Dd;             // [B, DK]
    float* dennew = numnew + (size_t)Bsz * DKd;         // [B, DK]

    char* ws = (char*)d_ws;
    unsigned short* mixed = (unsigned short*)ws;                       // 32 MB
    unsigned short* WkB   = (unsigned short*)(ws + (size_t)Bsz * Dd * 2);
    unsigned short* WfB   = WkB + (size_t)DKd * Dd;                    // +2 MB
    unsigned short* rwkv  = WfB + (size_t)Dd * DKd;                    // +2 MB

    k_prep<<<2048, 256, 0, stream>>>((const float4*)x, (const float4*)xprev, mixk,
                                     (const float4*)Wk, (const float4*)Wf,
                                     mixed, WkB, WfB);

    const int grid = (Bsz / 256) * (DKd / 256);   // 256 blocks, 1 per CU
    k_gemm1<<<grid, 512, 0, stream>>>(mixed, WkB, bk, num, den, bonus, decay,
                                      numnew, dennew, rwkv);
    k_gemm2<<<grid, 512, 0, stream>>>(rwkv, WfB, bf_, out);
}